// Round 5
// baseline (126.361 us; speedup 1.0000x reference)
//
#include <hip/hip_runtime.h>

// RenderingModel: scatter-add of 64x64 filters at N particle positions onto a
// 512x512 canvas (cropped). Gather formulation with a ZERO-PADDED filter bank:
//
//  1) pad_filters_kernel: builds fpad[256][128][128] in d_ws (filter centered,
//     32-wide zero border). For any tile pixel y,x and any hitting particle
//     (row,col), index (y-row+64, x-col+64) lies in [1,126]^2 -> phase-2 loads
//     need NO clamps and NO selects (pad zeros contribute exactly 0).
//     Also zeroes d_out (atomic epilogue needs zeros; harness poisons 0xAA).
//  2) render_tile_kernel: block = 32x32 tile x 1024-particle segment (grid.z=8).
//     Phase 1 compacts hits into LDS. Phase 2: thread owns 1 row x 4 cols; per
//     hit = ONE 16B load (SGPR base from readfirstlane-decoded hit + loop-
//     invariant vector offset) + 4 adds. Epilogue: 4 global fp32 atomicAdd.

#define H_  512
#define W_  512
#define FH_ 64
#define FW_ 64
#define NPARTS_ 256
#define PFH_ 128
#define PFW_ 128
#define TILE_ 32
#define THREADS_ 256
#define SEG_LEN_ 1024

// 4-byte-aligned float4: base alignment depends on col%4, so we must not
// promise 16B alignment. Compiler emits dwordx4 if the target allows
// misaligned VMEM, else splits -- both correct.
struct __attribute__((packed, aligned(4))) f4u { float x, y, z, w; };

__global__ __launch_bounds__(256)
void pad_filters_kernel(const float* __restrict__ filters,
                        float* __restrict__ fpad,
                        float* __restrict__ out) {
    const int part = blockIdx.x;          // 0..255
    const int t    = threadIdx.x;
    float4* dst = (float4*)(fpad + part * (PFH_ * PFW_));
    const float* src = filters + part * (FH_ * FW_);
#pragma unroll
    for (int it = 0; it < 16; ++it) {
        const int slot = t + 256 * it;        // float4 slot in [0, 4096)
        const int pr   = slot >> 5;           // padded row 0..127
        const int pc4  = (slot & 31) * 4;     // padded col (multiple of 4)
        float4 v = make_float4(0.f, 0.f, 0.f, 0.f);
        // interior iff pr in [32,96) and pc4 in [32,96); 32/96 are multiples
        // of 4 so a float4 slot is fully interior or fully pad.
        if (pr >= 32 && pr < 96 && pc4 >= 32 && pc4 < 96) {
            v = *(const float4*)(src + (pr - 32) * FW_ + (pc4 - 32));
        }
        dst[slot] = v;
    }
    // zero 4KB of d_out per block (256 blocks x 1024 floats = 512*512)
    ((float4*)out)[part * 256 + t] = make_float4(0.f, 0.f, 0.f, 0.f);
}

__global__ __launch_bounds__(THREADS_, 8)
void render_tile_kernel(const int* __restrict__ phw,
                        const float* __restrict__ fpad,
                        float* __restrict__ out, int n) {
    __shared__ unsigned int s_list[SEG_LEN_];
    __shared__ int s_cnt;

    const int t   = threadIdx.x;
    const int tx0 = blockIdx.x * TILE_;
    const int ty0 = blockIdx.y * TILE_;
    const int k0  = blockIdx.z * SEG_LEN_;
    const int k1  = (k0 + SEG_LEN_ < n) ? (k0 + SEG_LEN_) : n;

    if (t == 0) s_cnt = 0;
    __syncthreads();

    // ---- Phase 1: bbox test + compaction of this segment into LDS ----
    for (int k = k0 + t; k < k1; k += THREADS_) {
        const int part = phw[k * 3 + 0];
        const int row  = phw[k * 3 + 1];
        const int col  = phw[k * 3 + 2];
        const bool hit =
            (row >= ty0 - (FH_ / 2 - 1)) && (row <= ty0 + TILE_ - 1 + FH_ / 2) &&
            (col >= tx0 - (FW_ / 2 - 1)) && (col <= tx0 + TILE_ - 1 + FW_ / 2);
        if (hit) {
            const int idx = atomicAdd(&s_cnt, 1);
            // pack: part(8b) | row(9b) | col(9b)
            s_list[idx] = ((unsigned)part << 18) | ((unsigned)row << 9) | (unsigned)col;
        }
    }
    __syncthreads();
    const int cnt = s_cnt;

    // ---- Phase 2: thread owns row y = ty0 + (t>>3), cols x0..x0+3 ----
    const int x0 = tx0 + (t & 7) * 4;
    const int y  = ty0 + (t >> 3);
    // loop-invariant vector part of the pad address (elements)
    const int voff = y * PFW_ + x0;

    float acc0 = 0.f, acc1 = 0.f, acc2 = 0.f, acc3 = 0.f;

    auto body = [&](unsigned v) {
        const int part = (int)__builtin_amdgcn_readfirstlane(v >> 18);
        const int row  = (int)__builtin_amdgcn_readfirstlane((v >> 9) & 511u);
        const int col  = (int)__builtin_amdgcn_readfirstlane(v & 511u);
        // scalar base: fpad + part*128*128 + (64-row)*128 + (64-col)
        const float* __restrict__ f =
            fpad + part * (PFH_ * PFW_) + ((64 - row) * PFW_ + (64 - col));
        const f4u w = *(const f4u*)(f + voff);  // unconditional, pad-safe
        acc0 += w.x; acc1 += w.y; acc2 += w.z; acc3 += w.w;
    };

    int k = 0;
    for (; k + 4 <= cnt; k += 4) {
        const uint4 vv = *(const uint4*)&s_list[k];  // wave-uniform broadcast
        body(vv.x); body(vv.y); body(vv.z); body(vv.w);
    }
    for (; k < cnt; ++k) body(s_list[k]);

    // ---- Epilogue: combine segments via device-scope fp32 atomics ----
    float* o = out + y * W_ + x0;
    atomicAdd(o + 0, acc0);
    atomicAdd(o + 1, acc1);
    atomicAdd(o + 2, acc2);
    atomicAdd(o + 3, acc3);
}

extern "C" void kernel_launch(void* const* d_in, const int* in_sizes, int n_in,
                              void* d_out, int out_size, void* d_ws, size_t ws_size,
                              hipStream_t stream) {
    const int*   phw     = (const int*)d_in[0];
    const float* filters = (const float*)d_in[1];
    float*       out     = (float*)d_out;
    float*       fpad    = (float*)d_ws;   // 256*128*128*4 = 16 MB scratch
    const int n = in_sizes[0] / 3;

    pad_filters_kernel<<<NPARTS_, 256, 0, stream>>>(filters, fpad, out);

    const int segs = (n + SEG_LEN_ - 1) / SEG_LEN_;
    dim3 grid(W_ / TILE_, H_ / TILE_, segs);
    render_tile_kernel<<<grid, THREADS_, 0, stream>>>(phw, fpad, out, n);
}

// Round 6
// 107.428 us; speedup vs baseline: 1.1762x; 1.1762x over previous
//
#include <hip/hip_runtime.h>

// RenderingModel: scatter-add of 64x64 filters at N particle positions onto a
// 512x512 canvas (cropped). Gather formulation.
//
// R5 post-mortem: full fp32 128x128 padded bank = 16 MB >> 4 MiB L2/XCD ->
// FETCH_SIZE 18->180 MB, render 25->64 us. The pad trick only works if the
// bank stays L2-resident. R6: bank = bf16, COLUMN-padded only:
//   fbank[256][64][128] bf16 = 4 MB  (cols j+32, 32-col zero borders)
// -> column guards vanish (pad zeros), row handled by one med3 clamp + one
// compare + 4 value selects. Per hit per thread: ONE 8B load (4 consecutive
// bf16 cols) + ~18 VALU, traffic halved vs fp32 and L2-resident again.
//
// Pipeline: pad kernel builds the bank in d_ws and zeroes d_out; render block
// = 32x32 tile x 1024-particle segment (grid.z=8): phase 1 compacts hits into
// LDS (wave-uniform), phase 2 accumulates (hit decode via readfirstlane ->
// SGPR base), epilogue = 4 global fp32 atomicAdd per thread.

#define H_  512
#define W_  512
#define FH_ 64
#define FW_ 64
#define NPARTS_ 256
#define BW_ 128          // bank row width (col-padded)
#define TILE_ 32
#define THREADS_ 256
#define SEG_LEN_ 1024

// 4 consecutive bf16 filter cols; base alignment is only 2B (depends on
// col parity) so do not promise more. gfx950 global loads handle it.
struct __attribute__((packed, aligned(2))) b4u { unsigned short a, b, c, d; };

__device__ __forceinline__ unsigned short f2bf(float f) {
    unsigned u = __float_as_uint(f);
    return (unsigned short)((u + 0x7fffu + ((u >> 16) & 1u)) >> 16);  // RNE
}
__device__ __forceinline__ float bf2f(unsigned short h) {
    return __uint_as_float((unsigned)h << 16);
}

__global__ __launch_bounds__(256)
void pad_filters_kernel(const float* __restrict__ filters,
                        unsigned int* __restrict__ bank,   // bf16 pairs
                        float* __restrict__ out) {
    const int part = blockIdx.x;
    const int t    = threadIdx.x;
    unsigned int* dst = bank + part * (FH_ * BW_ / 2);      // 4096 uints/part
    const float* src  = filters + part * (FH_ * FW_);
#pragma unroll
    for (int it = 0; it < 16; ++it) {
        const int u   = t + 256 * it;     // uint slot in [0,4096)
        const int pr  = u >> 6;           // bank row 0..63
        const int jp  = (u & 63) * 2;     // bank col (even)
        unsigned lo = 0, hi = 0;
        if (jp >= 32 && jp < 96) {        // both cols interior or both pad
            const float* s = src + pr * FW_ + (jp - 32);
            lo = f2bf(s[0]);
            hi = f2bf(s[1]);
        }
        dst[u] = lo | (hi << 16);
    }
    // zero d_out (atomic epilogue needs zeros; harness poisons 0xAA)
    ((float4*)out)[part * 256 + t] = make_float4(0.f, 0.f, 0.f, 0.f);
}

__global__ __launch_bounds__(THREADS_, 8)
void render_tile_kernel(const int* __restrict__ phw,
                        const unsigned short* __restrict__ bank,
                        float* __restrict__ out, int n) {
    __shared__ unsigned int s_list[SEG_LEN_];
    __shared__ int s_cnt;

    const int t   = threadIdx.x;
    const int tx0 = blockIdx.x * TILE_;
    const int ty0 = blockIdx.y * TILE_;
    const int k0  = blockIdx.z * SEG_LEN_;
    const int k1  = (k0 + SEG_LEN_ < n) ? (k0 + SEG_LEN_) : n;

    if (t == 0) s_cnt = 0;
    __syncthreads();

    // ---- Phase 1: bbox test + compaction of this segment into LDS ----
    for (int k = k0 + t; k < k1; k += THREADS_) {
        const int part = phw[k * 3 + 0];
        const int row  = phw[k * 3 + 1];
        const int col  = phw[k * 3 + 2];
        const bool hit =
            (row >= ty0 - (FH_ / 2 - 1)) && (row <= ty0 + TILE_ - 1 + FH_ / 2) &&
            (col >= tx0 - (FW_ / 2 - 1)) && (col <= tx0 + TILE_ - 1 + FW_ / 2);
        if (hit) {
            const int idx = atomicAdd(&s_cnt, 1);
            // pack: part(8b) | row(9b) | col(9b)
            s_list[idx] = ((unsigned)part << 18) | ((unsigned)row << 9) | (unsigned)col;
        }
    }
    __syncthreads();
    const int cnt = s_cnt;

    // ---- Phase 2: thread owns row y = ty0 + (t>>3), cols x0..x0+3 ----
    const int x0 = tx0 + (t & 7) * 4;
    const int y  = ty0 + (t >> 3);
    const int xq = x0 + (FW_ / 2) + 32;   // bank col for this thread = xq - col
    const int yq = y + (FH_ / 2);         // filter row = yq - row

    float acc0 = 0.f, acc1 = 0.f, acc2 = 0.f, acc3 = 0.f;

    auto body = [&](unsigned v) {
        const int part = (int)__builtin_amdgcn_readfirstlane(v >> 18);
        const int row  = (int)__builtin_amdgcn_readfirstlane((v >> 9) & 511u);
        const int col  = (int)__builtin_amdgcn_readfirstlane(v & 511u);
        const unsigned short* __restrict__ f = bank + (part << 13);  // SGPR base

        const int i  = yq - row;                 // filter row, in [-31, 94]
        const int ic = min(max(i, 0), FH_ - 1);  // v_med3_i32
        const int jp = xq - col;                 // bank col, in [1, 123]
        const b4u w  = *(const b4u*)(f + (ic << 7) + jp);  // unconditional 8B
        const bool iok = (unsigned)i < (unsigned)FH_;
        acc0 += iok ? bf2f(w.a) : 0.f;           // col pad zeros are exact
        acc1 += iok ? bf2f(w.b) : 0.f;
        acc2 += iok ? bf2f(w.c) : 0.f;
        acc3 += iok ? bf2f(w.d) : 0.f;
    };

    int k = 0;
    for (; k + 4 <= cnt; k += 4) {
        const uint4 vv = *(const uint4*)&s_list[k];  // wave-uniform broadcast
        body(vv.x); body(vv.y); body(vv.z); body(vv.w);
    }
    for (; k < cnt; ++k) body(s_list[k]);

    // ---- Epilogue: combine segments via device-scope fp32 atomics ----
    float* o = out + y * W_ + x0;
    atomicAdd(o + 0, acc0);
    atomicAdd(o + 1, acc1);
    atomicAdd(o + 2, acc2);
    atomicAdd(o + 3, acc3);
}

extern "C" void kernel_launch(void* const* d_in, const int* in_sizes, int n_in,
                              void* d_out, int out_size, void* d_ws, size_t ws_size,
                              hipStream_t stream) {
    const int*   phw     = (const int*)d_in[0];
    const float* filters = (const float*)d_in[1];
    float*       out     = (float*)d_out;
    unsigned int* bank   = (unsigned int*)d_ws;   // 256*64*128*2B = 4 MB
    const int n = in_sizes[0] / 3;

    pad_filters_kernel<<<NPARTS_, 256, 0, stream>>>(filters, bank, out);

    const int segs = (n + SEG_LEN_ - 1) / SEG_LEN_;
    dim3 grid(W_ / TILE_, H_ / TILE_, segs);
    render_tile_kernel<<<grid, THREADS_, 0, stream>>>(
        phw, (const unsigned short*)bank, out, n);
}

// Round 7
// 89.106 us; speedup vs baseline: 1.4181x; 1.2056x over previous
//
#include <hip/hip_runtime.h>

// RenderingModel: scatter-add of 64x64 filters at N particle positions onto a
// 512x512 canvas (cropped). Gather formulation, bf16 col-padded bank (4 MB,
// L2-resident -- R5 proved >4MB thrashes; R6 confirmed FETCH back to 17.5MB).
//
// R6 post-mortem: 45.5us @ VALUBusy 18% = latency-bound; R6 cut MLP to 1 load
// per hit-body. R7 restructure:
//  - hit list SPLIT ACROSS WAVES (wave w takes hits w, w+4, ...): each wave
//    covers the FULL 32x32 tile (thread owns a 4x4 px patch) -> 4x fewer
//    serialized hit-iterations per wave, 4 independent 8B loads per body,
//    2-body unroll = 8 loads in flight per thread.
//  - pure-VALU hit decode (no readfirstlane): shorter LDS->VMEM chain.
//  - row guard: cndmask the BYTE OFFSET to the part's col-pad zero region
//    (bank cols 0..31 of row 0 are zeros) -- no per-element selects.
//  - waves' partial tiles combined via LDS (16KB) then 4 atomics/thread:
//    1M atomics total (half of R6).
// Bank: fbank[256][64][128] bf16; filter col j at bank col j+32; rows unpadded.

#define H_  512
#define W_  512
#define FH_ 64
#define FW_ 64
#define NPARTS_ 256
#define BW_ 128
#define TILE_ 32
#define THREADS_ 256
#define SEG_LEN_ 2048
#define SEGS_ 4

// 8B of bf16 bank data at only-2B-guaranteed alignment (col parity random).
struct __attribute__((packed, aligned(2))) b8u { unsigned int x, y; };

__device__ __forceinline__ unsigned short f2bf(float f) {
    unsigned u = __float_as_uint(f);
    return (unsigned short)((u + 0x7fffu + ((u >> 16) & 1u)) >> 16);  // RNE
}
__device__ __forceinline__ float bf_lo(unsigned int u) {
    return __uint_as_float(u << 16);
}
__device__ __forceinline__ float bf_hi(unsigned int u) {
    return __uint_as_float(u & 0xffff0000u);
}

__global__ __launch_bounds__(256)
void pad_filters_kernel(const float* __restrict__ filters,
                        unsigned int* __restrict__ bank,   // bf16 pairs
                        float* __restrict__ out) {
    const int part = blockIdx.x;
    const int t    = threadIdx.x;
    unsigned int* dst = bank + part * (FH_ * BW_ / 2);      // 4096 uints/part
    const float* src  = filters + part * (FH_ * FW_);
#pragma unroll
    for (int it = 0; it < 16; ++it) {
        const int u  = t + 256 * it;      // uint slot in [0,4096)
        const int pr = u >> 6;            // bank row 0..63
        const int jp = (u & 63) * 2;      // bank col (even)
        unsigned lo = 0, hi = 0;
        if (jp >= 32 && jp < 96) {        // both cols interior or both pad
            const float* s = src + pr * FW_ + (jp - 32);
            lo = f2bf(s[0]);
            hi = f2bf(s[1]);
        }
        dst[u] = lo | (hi << 16);
    }
    // zero d_out (atomic epilogue needs zeros; harness poisons 0xAA)
    ((float4*)out)[part * 256 + t] = make_float4(0.f, 0.f, 0.f, 0.f);
}

__global__ __launch_bounds__(THREADS_, 4)
void render_tile_kernel(const int* __restrict__ phw,
                        const unsigned short* __restrict__ bank,
                        float* __restrict__ out, int n) {
    __shared__ unsigned int s_list[SEG_LEN_];
    __shared__ float s_red[16 * 4 * 64];   // [slot][wave][lane]
    __shared__ int s_cnt;

    const int t   = threadIdx.x;
    const int tx0 = blockIdx.x * TILE_;
    const int ty0 = blockIdx.y * TILE_;
    const int k0  = blockIdx.z * SEG_LEN_;
    const int k1  = (k0 + SEG_LEN_ < n) ? (k0 + SEG_LEN_) : n;

    if (t == 0) s_cnt = 0;
    __syncthreads();

    // ---- Phase 1: bbox test + compaction of this segment into LDS ----
    for (int k = k0 + t; k < k1; k += THREADS_) {
        const int part = phw[k * 3 + 0];
        const int row  = phw[k * 3 + 1];
        const int col  = phw[k * 3 + 2];
        const bool hit =
            (row >= ty0 - (FH_ / 2 - 1)) && (row <= ty0 + TILE_ - 1 + FH_ / 2) &&
            (col >= tx0 - (FW_ / 2 - 1)) && (col <= tx0 + TILE_ - 1 + FW_ / 2);
        if (hit) {
            const int idx = atomicAdd(&s_cnt, 1);
            // pack: part(8b) | row(9b) | col(9b)
            s_list[idx] = ((unsigned)part << 18) | ((unsigned)row << 9) | (unsigned)col;
        }
    }
    __syncthreads();
    const int cnt = s_cnt;

    // ---- Phase 2: wave w handles hits w, w+4, ... over the FULL tile ----
    // Thread (lane) owns a 4x4 px patch: rows r0..r0+3, cols c0..c0+3.
    const int w    = t >> 6;
    const int lane = t & 63;
    const int r0   = (lane >> 3) * 4;          // 0,4,...,28
    const int c0   = (lane & 7) * 4;           // 0,4,...,28
    const int yq0  = ty0 + r0 + (FH_ / 2);     // filter row i = yq0 - row (+q)
    const int xq2  = (tx0 + c0 + (FW_ / 2) + 32) * 2;  // byte col in bank row
    const char* bankb = (const char*)bank;

    float acc[16];
#pragma unroll
    for (int s = 0; s < 16; ++s) acc[s] = 0.f;

    auto body = [&](unsigned v) {
        const int row  = (int)((v >> 9) & 511u);
        const unsigned col2  = (v & 511u) << 1;
        const unsigned pbase = (v >> 18) << 14;        // part * 16384 bytes
        const unsigned off0  = pbase + (unsigned)xq2 - col2;  // row-0 byte addr
        const int i0 = yq0 - row;                      // filter row for q=0
#pragma unroll
        for (int q = 0; q < 4; ++q) {
            const int iq = i0 + q;
            const unsigned off = off0 + (unsigned)iq * 256u;
            // invalid row -> part's row-0 col-pad zeros (bytes pbase..pbase+7)
            const unsigned offq = ((unsigned)iq < (unsigned)FH_) ? off : pbase;
            const b8u wv = *(const b8u*)(bankb + offq);  // unconditional 8B
            acc[q * 4 + 0] += bf_lo(wv.x);
            acc[q * 4 + 1] += bf_hi(wv.x);
            acc[q * 4 + 2] += bf_lo(wv.y);
            acc[q * 4 + 3] += bf_hi(wv.y);
        }
    };

    int k = w;
    for (; k + 4 < cnt; k += 8) {        // 2 hits in flight (8 loads/thread)
        const unsigned a = s_list[k];
        const unsigned b = s_list[k + 4];
        body(a);
        body(b);
    }
    if (k < cnt) body(s_list[k]);

    // ---- Phase 3: combine the 4 waves' partial tiles via LDS ----
#pragma unroll
    for (int s = 0; s < 16; ++s)
        s_red[(s * 4 + w) * 64 + lane] = acc[s];       // lane-contiguous
    __syncthreads();

    // Thread (w,lane) reduces slots s = w*4+e over all 4 waves:
    // px row = (lane>>3)*4 + w, cols = (lane&7)*4 + e  (e=0..3 consecutive)
    float sum[4];
#pragma unroll
    for (int e = 0; e < 4; ++e) {
        const int s = w * 4 + e;
        sum[e] = s_red[(s * 4 + 0) * 64 + lane] + s_red[(s * 4 + 1) * 64 + lane]
               + s_red[(s * 4 + 2) * 64 + lane] + s_red[(s * 4 + 3) * 64 + lane];
    }
    const int rr = (lane >> 3) * 4 + w;
    const int cc = (lane & 7) * 4;
    float* o = out + (ty0 + rr) * W_ + (tx0 + cc);
    atomicAdd(o + 0, sum[0]);
    atomicAdd(o + 1, sum[1]);
    atomicAdd(o + 2, sum[2]);
    atomicAdd(o + 3, sum[3]);
}

extern "C" void kernel_launch(void* const* d_in, const int* in_sizes, int n_in,
                              void* d_out, int out_size, void* d_ws, size_t ws_size,
                              hipStream_t stream) {
    const int*   phw     = (const int*)d_in[0];
    const float* filters = (const float*)d_in[1];
    float*       out     = (float*)d_out;
    unsigned int* bank   = (unsigned int*)d_ws;   // 256*64*128*2B = 4 MB
    const int n = in_sizes[0] / 3;

    pad_filters_kernel<<<NPARTS_, 256, 0, stream>>>(filters, bank, out);

    const int segs = (n + SEG_LEN_ - 1) / SEG_LEN_;   // = 4 at N=8192
    dim3 grid(W_ / TILE_, H_ / TILE_, segs);
    render_tile_kernel<<<grid, THREADS_, 0, stream>>>(
        phw, (const unsigned short*)bank, out, n);
}